// Round 6
// baseline (552.552 us; speedup 1.0000x reference)
//
#include <hip/hip_runtime.h>
#include <hip/hip_bf16.h>

// Problem constants: B=4, S=2048, D=1024, H=16, DEPTH=64
#define Bn 4
#define Sn 2048
#define Dn 1024
#define Hn 16
#define DEPTHn 64

typedef __attribute__((ext_vector_type(8))) short short8;   // 8 bf16 = 4 VGPRs
typedef __attribute__((ext_vector_type(4))) float float4v;  // MFMA 16x16 C/D

#define LOG2E 1.44269504088896340736f
#define C16   23.083120654223414f   // 16 * log2(e); fixed softmax max M=16

__device__ __forceinline__ void load_lds16(const void* g, void* l) {
  __builtin_amdgcn_global_load_lds(
      (const __attribute__((address_space(1))) unsigned int*)g,
      (__attribute__((address_space(3))) unsigned int*)l, 16, 0, 0);
}

// ---------------- cast x & y -> bf16 in one launch ----------------
__global__ __launch_bounds__(256) void cast_xy(const float* __restrict__ x,
                                               const float* __restrict__ y,
                                               __hip_bfloat16* __restrict__ out) {
  int i = blockIdx.x * blockDim.x + threadIdx.x;  // 2 * 1048576
  const float* src = (i >> 20) ? y : x;
  int j = i & 1048575;
  float v[8];
  *(float4*)&v[0] = ((const float4*)src)[2 * j];
  *(float4*)&v[4] = ((const float4*)src)[2 * j + 1];
  union { __hip_bfloat16 h[8]; short8 s; } u;
#pragma unroll
  for (int k = 0; k < 8; ++k) u.h[k] = __float2bfloat16(v[k]);
  ((short8*)out)[i] = u.s;
}

// ---- all 4 weight casts in one launch (wq gets depth^-0.5 folded) ----
__global__ __launch_bounds__(256) void cast_w(const float* __restrict__ wq,
                                              const float* __restrict__ wk,
                                              const float* __restrict__ wv,
                                              const float* __restrict__ wo,
                                              __hip_bfloat16* __restrict__ out) {
  int i = blockIdx.x * blockDim.x + threadIdx.x;  // 524288
  int which = i >> 17, j = i & 131071;
  const float* src = (which == 0) ? wq : (which == 1) ? wk : (which == 2) ? wv : wo;
  float scale = (which == 0) ? 0.125f : 1.0f;
  float v[8];
  *(float4*)&v[0] = ((const float4*)src)[2 * j];
  *(float4*)&v[4] = ((const float4*)src)[2 * j + 1];
  union { __hip_bfloat16 h[8]; short8 s; } u;
#pragma unroll
  for (int k = 0; k < 8; ++k) u.h[k] = __float2bfloat16(v[k] * scale);
  ((short8*)out)[i] = u.s;
}

// ------------- bias -> fragment-ordered fp32, pre-fused: b*log2e - 16*log2e --
__global__ __launch_bounds__(256) void rearrange_bias(const float* __restrict__ in,
                                                      float* __restrict__ out) {
  int t = blockIdx.x * blockDim.x + threadIdx.x;  // 524288
  int r = t & 3, lane = (t >> 2) & 63, wm = (t >> 8) & 15;
  int jti = (t >> 12) & 15, qb = (t >> 16) & 7;
  int wave = wm >> 2, mt = wm & 3, quad = lane >> 4, l16 = lane & 15;
  int row = qb * 256 + wave * 64 + mt * 16 + quad * 4 + r;
  const float* src = in + (size_t)row * Sn + jti * 128 + l16;
  float4v o0, o1;
#pragma unroll
  for (int j = 0; j < 4; ++j) o0[j] = fmaf(src[j * 16], LOG2E, -C16);
#pragma unroll
  for (int j = 0; j < 4; ++j) o1[j] = fmaf(src[(j + 4) * 16], LOG2E, -C16);
  ((float4v*)out)[t * 2] = o0;
  ((float4v*)out)[t * 2 + 1] = o1;
}

// ------- fused QKV NT GEMM: grid (64, 24), Wqkv = [Wq;Wk;Wv] contiguous ------
// bn 0..7  -> Q  -> [B,H,S,64], d ^ (s&7)<<3           (A = xb)
// bn 8..15 -> K  -> [B,H,S,64], d ^ (s&7)<<3           (A = yb)
// bn 16..23-> V  -> [B,H,64,S], sigma+xor inner layout via LDS transpose (A=yb)
__global__ __launch_bounds__(256) void gemm_qkv(const __hip_bfloat16* __restrict__ Xb,
                                                const __hip_bfloat16* __restrict__ Yb,
                                                const __hip_bfloat16* __restrict__ Wqkv,
                                                __hip_bfloat16* __restrict__ Qb,
                                                __hip_bfloat16* __restrict__ Kb,
                                                __hip_bfloat16* __restrict__ Vtb) {
  constexpr int Kdim = 1024;
  __shared__ char pool[128 * 129 * 2];   // 33 KB: As+Bs during K-loop, stage after
  __hip_bfloat16* As = (__hip_bfloat16*)pool;
  __hip_bfloat16* Bs = As + 128 * 64;
  __hip_bfloat16* Sg = (__hip_bfloat16*)pool;  // stage[row*129 + col], aliased

  const int tid = threadIdx.x;
  const int wave = tid >> 6, lane = tid & 63;
  const int quad = lane >> 4, l16 = lane & 15;
  const int bm = blockIdx.x, bn = blockIdx.y;
  const int sel = bn >> 3;  // 0=Q 1=K 2=V
  const int wm = (wave & 1) * 64, wn = (wave >> 1) * 64;
  const __hip_bfloat16* A = (sel == 0) ? Xb : Yb;

  const __hip_bfloat16* aptr[4];
  const __hip_bfloat16* bptr[4];
#pragma unroll
  for (int i = 0; i < 4; ++i) {
    int c = wave * 4 + i;
    aptr[i] = A + (size_t)(bm * 128 + c * 8 + (lane >> 3)) * Kdim + (lane & 7) * 8;
    bptr[i] = Wqkv + (size_t)(bn * 128 + c * 8 + (lane >> 3)) * Kdim + (lane & 7) * 8;
  }

  float4v acc[4][4];
#pragma unroll
  for (int i = 0; i < 4; ++i)
#pragma unroll
    for (int j = 0; j < 4; ++j) acc[i][j] = (float4v){0.f, 0.f, 0.f, 0.f};

  for (int kt = 0; kt < Kdim / 64; ++kt) {
    __syncthreads();
#pragma unroll
    for (int i = 0; i < 4; ++i) {
      int c = wave * 4 + i;
      load_lds16(aptr[i] + kt * 64, &As[c * 512]);
      load_lds16(bptr[i] + kt * 64, &Bs[c * 512]);
    }
    __syncthreads();
#pragma unroll
    for (int ks = 0; ks < 2; ++ks) {
      short8 af[4], bf[4];
#pragma unroll
      for (int i = 0; i < 4; ++i)
        af[i] = *(const short8*)&As[(wm + i * 16 + l16) * 64 + ks * 32 + quad * 8];
#pragma unroll
      for (int j = 0; j < 4; ++j)
        bf[j] = *(const short8*)&Bs[(wn + j * 16 + l16) * 64 + ks * 32 + quad * 8];
#pragma unroll
      for (int i = 0; i < 4; ++i)
#pragma unroll
        for (int j = 0; j < 4; ++j)
          acc[i][j] = __builtin_amdgcn_mfma_f32_16x16x32_bf16(af[i], bf[j], acc[i][j], 0, 0, 0);
    }
  }

  const int b = bm >> 4;  // batch (16 s-tiles per batch)
  if (sel < 2) {
    // Q / K: granule-coalesced direct store
    __hip_bfloat16* dst = (sel == 0) ? Qb : Kb;
    const int nbase = (bn & 7) * 128;
#pragma unroll
    for (int i = 0; i < 4; ++i)
#pragma unroll
      for (int j = 0; j < 4; ++j)
#pragma unroll
        for (int r = 0; r < 4; ++r) {
          int row = bm * 128 + wm + i * 16 + quad * 4 + r;
          int col = nbase + wn + j * 16 + l16;
          int s = row & 2047, h = col >> 6, d = col & 63;
          int d2 = d ^ ((s & 7) << 3);
          dst[(((size_t)b * Hn + h) * Sn + s) * DEPTHn + d2] = __float2bfloat16(acc[i][j][r]);
        }
  } else {
    // V: LDS transpose -> coalesced b128 stores in sigma+xor layout
    __syncthreads();  // everyone done reading As/Bs
#pragma unroll
    for (int i = 0; i < 4; ++i)
#pragma unroll
      for (int j = 0; j < 4; ++j)
#pragma unroll
        for (int r = 0; r < 4; ++r) {
          int row = wm + i * 16 + quad * 4 + r;       // local s 0..127
          int col = wn + j * 16 + l16;                // local n 0..127
          Sg[row * 129 + col] = __float2bfloat16(acc[i][j][r]);
        }
    __syncthreads();
    const int s_tile = (bm & 15) * 128;
#pragma unroll
    for (int iter = 0; iter < 8; ++iter) {
      int id = iter * 256 + tid;        // 2048 b128 outputs
      int chunk = id & 15, lcol = id >> 4;
      int hg = (bn - 16) * 2 + (lcol >> 6), d = lcol & 63;
      int c = chunk ^ (d & 7);
      union { __hip_bfloat16 h[8]; short8 s8; } pu;
#pragma unroll
      for (int i = 0; i < 8; ++i) pu.h[i] = Sg[(i * 16 + c) * 129 + lcol];
      *(short8*)&Vtb[(((size_t)b * Hn + hg) * DEPTHn + d) * Sn + s_tile + chunk * 8] = pu.s8;
    }
  }
}

// ---------------- out-projection NT GEMM: fp32 output ----------------
__global__ __launch_bounds__(256) void gemm_out(const __hip_bfloat16* __restrict__ A,
                                                const __hip_bfloat16* __restrict__ B,
                                                float* __restrict__ Cf) {
  constexpr int Kdim = 1024;
  __shared__ __hip_bfloat16 As[128 * 64];
  __shared__ __hip_bfloat16 Bs[128 * 64];
  const int tid = threadIdx.x;
  const int wave = tid >> 6, lane = tid & 63;
  const int quad = lane >> 4, l16 = lane & 15;
  const int bm = blockIdx.x, bn = blockIdx.y;
  const int wm = (wave & 1) * 64, wn = (wave >> 1) * 64;

  const __hip_bfloat16* aptr[4];
  const __hip_bfloat16* bptr[4];
#pragma unroll
  for (int i = 0; i < 4; ++i) {
    int c = wave * 4 + i;
    aptr[i] = A + (size_t)(bm * 128 + c * 8 + (lane >> 3)) * Kdim + (lane & 7) * 8;
    bptr[i] = B + (size_t)(bn * 128 + c * 8 + (lane >> 3)) * Kdim + (lane & 7) * 8;
  }

  float4v acc[4][4];
#pragma unroll
  for (int i = 0; i < 4; ++i)
#pragma unroll
    for (int j = 0; j < 4; ++j) acc[i][j] = (float4v){0.f, 0.f, 0.f, 0.f};

  for (int kt = 0; kt < Kdim / 64; ++kt) {
    __syncthreads();
#pragma unroll
    for (int i = 0; i < 4; ++i) {
      int c = wave * 4 + i;
      load_lds16(aptr[i] + kt * 64, &As[c * 512]);
      load_lds16(bptr[i] + kt * 64, &Bs[c * 512]);
    }
    __syncthreads();
#pragma unroll
    for (int ks = 0; ks < 2; ++ks) {
      short8 af[4], bf[4];
#pragma unroll
      for (int i = 0; i < 4; ++i)
        af[i] = *(const short8*)&As[(wm + i * 16 + l16) * 64 + ks * 32 + quad * 8];
#pragma unroll
      for (int j = 0; j < 4; ++j)
        bf[j] = *(const short8*)&Bs[(wn + j * 16 + l16) * 64 + ks * 32 + quad * 8];
#pragma unroll
      for (int i = 0; i < 4; ++i)
#pragma unroll
        for (int j = 0; j < 4; ++j)
          acc[i][j] = __builtin_amdgcn_mfma_f32_16x16x32_bf16(af[i], bf[j], acc[i][j], 0, 0, 0);
    }
  }
#pragma unroll
  for (int i = 0; i < 4; ++i)
#pragma unroll
    for (int j = 0; j < 4; ++j)
#pragma unroll
      for (int r = 0; r < 4; ++r) {
        int row = bm * 128 + wm + i * 16 + quad * 4 + r;
        int col = bn * 128 + wn + j * 16 + l16;
        Cf[(size_t)row * 1024 + col] = acc[i][j][r];
      }
}

// ---------------- flash attention: 256 q-rows/block, sigma-packed P ----------
// 1-D grid 512, XCD-swizzled.
// Compute structure = round-0 baseline (32-row Ps, fused m2 softmax+PV, per-r
// JIT bias) — the shape PROVEN to fit (256,2) without spill (128 V + ~64 A).
// Staging pipeline kept: Ks double-buffered (prefetch at top of iter, drained
// by end barrier), Vts staged after end barrier, published at the mid barrier
// after QK^T(mtp=0).  LDS = 32+16+32 = 80 KB exactly -> 2 blocks/CU (160 KB).
// History: r2 (256,2)+bb[8] spilled 535 MB; r3/r5 (256,1) allocator used 196 V
// -> 1 block/CU, 221 us.  Budget must be forced via (256,2); demand must match
// the baseline structure.
__global__ __launch_bounds__(256, 2) void flash_attn(const __hip_bfloat16* __restrict__ Q,
                                                     const __hip_bfloat16* __restrict__ Kh,
                                                     const __hip_bfloat16* __restrict__ Vt,
                                                     const float* __restrict__ biasR,
                                                     __hip_bfloat16* __restrict__ O) {
  __shared__ __hip_bfloat16 Ks[2][128 * 64];   // 32 KB double-buffered K
  __shared__ __hip_bfloat16 Vts[64 * 128];     // 16 KB (sigma-ordered cols)
  __shared__ __hip_bfloat16 Ps[4][32 * 128];   // 32 KB, per-wave 32 rows
  const int tid = threadIdx.x;
  const int wave = tid >> 6, lane = tid & 63;
  const int quad = lane >> 4, l16 = lane & 15;
  const int swk = (l16 & 7) << 3;
  const int lin = blockIdx.x;
  const int bh = (lin & 7) * 8 + ((lin >> 3) & 7);   // XCD-locality swizzle
  const int qb = lin >> 6;
  const int q0 = qb * 256;
  const __hip_bfloat16* Qp = Q + (size_t)bh * Sn * DEPTHn;
  const __hip_bfloat16* Kp = Kh + (size_t)bh * Sn * DEPTHn;
  const __hip_bfloat16* Vp = Vt + (size_t)bh * DEPTHn * Sn;

  short8 qf[4][2];
#pragma unroll
  for (int mt = 0; mt < 4; ++mt)
#pragma unroll
    for (int ks = 0; ks < 2; ++ks)
      qf[mt][ks] = *(const short8*)&Qp[(size_t)(q0 + wave * 64 + mt * 16 + l16) * 64 +
                                       ((ks * 32 + quad * 8) ^ swk)];

  float l_i[4][4];
  float4v oacc[4][4];
#pragma unroll
  for (int mt = 0; mt < 4; ++mt)
#pragma unroll
    for (int r = 0; r < 4; ++r) l_i[mt][r] = 0.f;
#pragma unroll
  for (int mt = 0; mt < 4; ++mt)
#pragma unroll
    for (int nt = 0; nt < 4; ++nt) oacc[mt][nt] = (float4v){0.f, 0.f, 0.f, 0.f};

  const int koff = (lane >> 3) * 64 + (lane & 7) * 8;
  const int voff = (lane >> 4) * Sn + l16 * 8;

  // prologue: stage tile 0 (K -> buf0, V -> Vts), publish
#pragma unroll
  for (int i = 0; i < 4; ++i) {
    int c = wave * 4 + i;
    load_lds16(Kp + (size_t)(c * 8) * 64 + koff, &Ks[0][c * 512]);
    load_lds16(Vp + (size_t)(c * 4) * Sn + voff, &Vts[c * 512]);
  }
  __syncthreads();

  for (int jti = 0; jti < 16; ++jti) {
    const int cur = jti & 1;
    // prefetch next K tile into the other buffer (drained by the end barrier)
    if (jti < 15) {
      const int j0n = (jti + 1) * 128;
#pragma unroll
      for (int i = 0; i < 4; ++i) {
        int c = wave * 4 + i;
        load_lds16(Kp + (size_t)(j0n + c * 8) * 64 + koff, &Ks[cur ^ 1][c * 512]);
      }
    }

#pragma unroll
    for (int mtp = 0; mtp < 2; ++mtp) {
      float4v sacc[2][8];
#pragma unroll
      for (int m2 = 0; m2 < 2; ++m2)
#pragma unroll
        for (int jt = 0; jt < 8; ++jt) sacc[m2][jt] = (float4v){0.f, 0.f, 0.f, 0.f};
      __builtin_amdgcn_s_setprio(1);
#pragma unroll
      for (int ks = 0; ks < 2; ++ks) {
        short8 kf[8];
#pragma unroll
        for (int jt = 0; jt < 8; ++jt)
          kf[jt] = *(const short8*)&Ks[cur][(jt * 16 + l16) * 64 + ((ks * 32 + quad * 8) ^ swk)];
#pragma unroll
        for (int m2 = 0; m2 < 2; ++m2)
#pragma unroll
          for (int jt = 0; jt < 8; ++jt)
            sacc[m2][jt] = __builtin_amdgcn_mfma_f32_16x16x32_bf16(qf[mtp * 2 + m2][ks], kf[jt],
                                                                   sacc[m2][jt], 0, 0, 0);
      }
      __builtin_amdgcn_s_setprio(0);
      if (mtp == 0) __syncthreads();  // publish Vts(jti); V-stage latency hid under QK^T

#pragma unroll
      for (int m2 = 0; m2 < 2; ++m2) {
        const int mt = mtp * 2 + m2;
        const float4v* bp = (const float4v*)biasR +
                            ((((size_t)(qb * 16 + jti) * 16 + wave * 4 + mt) * 64 + lane) << 3);
#pragma unroll
        for (int r = 0; r < 4; ++r) {
          float4v b0 = bp[r * 2], b1 = bp[r * 2 + 1];
          float ls = 0.f;
          union { __hip_bfloat16 h[8]; short8 s8; } pu;
#pragma unroll
          for (int jt = 0; jt < 8; ++jt) {
            float bb = (jt < 4) ? b0[jt] : b1[jt - 4];
            float p = __builtin_amdgcn_exp2f(fmaf(sacc[m2][jt][r], LOG2E, bb));
            ls += p;
            pu.h[jt] = __float2bfloat16(p);
          }
          l_i[mt][r] += ls;
          const int prow = m2 * 16 + quad * 4 + r;
          *(short8*)&Ps[wave][prow * 128 + ((l16 ^ (prow & 7)) << 3)] = pu.s8;
        }
      }

      __builtin_amdgcn_s_setprio(1);
#pragma unroll
      for (int ks = 0; ks < 4; ++ks) {
        short8 vf[4];
#pragma unroll
        for (int nt = 0; nt < 4; ++nt)
          vf[nt] = *(const short8*)&Vts[(nt * 16 + l16) * 128 + ((ks * 32 + quad * 8) ^ swk)];
#pragma unroll
        for (int m2 = 0; m2 < 2; ++m2) {
          short8 pf = *(const short8*)&Ps[wave][(m2 * 16 + l16) * 128 +
                                               ((ks * 32 + quad * 8) ^ swk)];
#pragma unroll
          for (int nt = 0; nt < 4; ++nt)
            oacc[mtp * 2 + m2][nt] =
                __builtin_amdgcn_mfma_f32_16x16x32_bf16(pf, vf[nt], oacc[mtp * 2 + m2][nt], 0, 0, 0);
        }
      }
      __builtin_amdgcn_s_setprio(0);
    }
    __syncthreads();  // end barrier: publishes Ks[cur^1], all Vts/Ps reads done
    // stage next V tile into the (now idle) single buffer; published at next mid barrier
    if (jti < 15) {
      const int j0n = (jti + 1) * 128;
#pragma unroll
      for (int i = 0; i < 4; ++i) {
        int c = wave * 4 + i;
        load_lds16(Vp + (size_t)(c * 4) * Sn + j0n + voff, &Vts[c * 512]);
      }
    }
  }

  const int b = bh >> 4, h = bh & 15;
#pragma unroll
  for (int mt = 0; mt < 4; ++mt) {
    float inv[4];
#pragma unroll
    for (int r = 0; r < 4; ++r) {
      float l = l_i[mt][r];
#pragma unroll
      for (int off = 1; off < 16; off <<= 1) l += __shfl_xor(l, off, 64);
      inv[r] = __builtin_amdgcn_rcpf(l);
    }
#pragma unroll
    for (int nt = 0; nt < 4; ++nt)
#pragma unroll
      for (int r = 0; r < 4; ++r) {
        int s = q0 + wave * 64 + mt * 16 + quad * 4 + r;
        int d = nt * 16 + l16;
        O[((size_t)b * Sn + s) * Dn + h * 64 + d] = __float2bfloat16(oacc[mt][nt][r] * inv[r]);
      }
  }
}

// ---------------- host ----------------
extern "C" void kernel_launch(void* const* d_in, const int* in_sizes, int n_in,
                              void* d_out, int out_size, void* d_ws, size_t ws_size,
                              hipStream_t stream) {
  const float* x = (const float*)d_in[0];
  const float* y = (const float*)d_in[1];
  const float* bias = (const float*)d_in[2];
  const float* Wq = (const float*)d_in[3];
  const float* Wk = (const float*)d_in[4];
  const float* Wv = (const float*)d_in[5];
  const float* Wo = (const float*)d_in[6];
  float* out = (float*)d_out;

  const size_t SZ_XY = (size_t)Bn * Sn * Dn * 2;     // 16 MB bf16
  const size_t SZ_W = (size_t)Dn * Dn * 2;           // 2 MB
  const size_t SZ_BIASF = (size_t)Sn * Sn * 4;       // 16 MB fp32

  char* p = (char*)d_ws;
  __hip_bfloat16* xb = (__hip_bfloat16*)p;      p += SZ_XY;   // xb,yb contiguous
  __hip_bfloat16* yb = (__hip_bfloat16*)p;      p += SZ_XY;
  __hip_bfloat16* wqkv = (__hip_bfloat16*)p;    p += 3 * SZ_W;  // Wq|Wk|Wv contiguous
  __hip_bfloat16* wob = (__hip_bfloat16*)p;     p += SZ_W;
  float* biasR = (float*)p;                     p += SZ_BIASF;
  __hip_bfloat16* Qb = (__hip_bfloat16*)p;      p += SZ_XY;
  __hip_bfloat16* Kb = (__hip_bfloat16*)p;      p += SZ_XY;
  __hip_bfloat16* Vtb = (__hip_bfloat16*)p;     p += SZ_XY;
  __hip_bfloat16* attnb = (__hip_bfloat16*)p;   p += SZ_XY;

  cast_xy<<<2 * 1048576 / 256, 256, 0, stream>>>(x, y, xb);
  cast_w<<<(4 * Dn * Dn / 8) / 256, 256, 0, stream>>>(Wq, Wk, Wv, Wo, wqkv);
  rearrange_bias<<<(Sn * Sn / 8) / 256, 256, 0, stream>>>(bias, biasR);

  gemm_qkv<<<dim3(64, 24), 256, 0, stream>>>(xb, yb, wqkv, Qb, Kb, Vtb);

  flash_attn<<<512, 256, 0, stream>>>(Qb, Kb, Vtb, biasR, attnb);

  gemm_out<<<dim3(64, 8), 256, 0, stream>>>(attnb, wob, out);
}

// Round 7
// 392.110 us; speedup vs baseline: 1.4092x; 1.4092x over previous
//
#include <hip/hip_runtime.h>
#include <hip/hip_bf16.h>

// Problem constants: B=4, S=2048, D=1024, H=16, DEPTH=64
#define Bn 4
#define Sn 2048
#define Dn 1024
#define Hn 16
#define DEPTHn 64

typedef __attribute__((ext_vector_type(8))) short short8;   // 8 bf16 = 4 VGPRs
typedef __attribute__((ext_vector_type(4))) float float4v;  // MFMA 16x16 C/D

#define LOG2E 1.44269504088896340736f
#define C16   23.083120654223414f   // 16 * log2(e); fixed softmax max M=16

__device__ __forceinline__ void load_lds16(const void* g, void* l) {
  __builtin_amdgcn_global_load_lds(
      (const __attribute__((address_space(1))) unsigned int*)g,
      (__attribute__((address_space(3))) unsigned int*)l, 16, 0, 0);
}

// ---------------- cast x & y -> bf16 in one launch ----------------
__global__ __launch_bounds__(256) void cast_xy(const float* __restrict__ x,
                                               const float* __restrict__ y,
                                               __hip_bfloat16* __restrict__ out) {
  int i = blockIdx.x * blockDim.x + threadIdx.x;  // 2 * 1048576
  const float* src = (i >> 20) ? y : x;
  int j = i & 1048575;
  float v[8];
  *(float4*)&v[0] = ((const float4*)src)[2 * j];
  *(float4*)&v[4] = ((const float4*)src)[2 * j + 1];
  union { __hip_bfloat16 h[8]; short8 s; } u;
#pragma unroll
  for (int k = 0; k < 8; ++k) u.h[k] = __float2bfloat16(v[k]);
  ((short8*)out)[i] = u.s;
}

// ---- all 4 weight casts in one launch (wq gets depth^-0.5 folded) ----
__global__ __launch_bounds__(256) void cast_w(const float* __restrict__ wq,
                                              const float* __restrict__ wk,
                                              const float* __restrict__ wv,
                                              const float* __restrict__ wo,
                                              __hip_bfloat16* __restrict__ out) {
  int i = blockIdx.x * blockDim.x + threadIdx.x;  // 524288
  int which = i >> 17, j = i & 131071;
  const float* src = (which == 0) ? wq : (which == 1) ? wk : (which == 2) ? wv : wo;
  float scale = (which == 0) ? 0.125f : 1.0f;
  float v[8];
  *(float4*)&v[0] = ((const float4*)src)[2 * j];
  *(float4*)&v[4] = ((const float4*)src)[2 * j + 1];
  union { __hip_bfloat16 h[8]; short8 s; } u;
#pragma unroll
  for (int k = 0; k < 8; ++k) u.h[k] = __float2bfloat16(v[k] * scale);
  ((short8*)out)[i] = u.s;
}

// ------------- bias -> fragment-ordered fp32, pre-fused: b*log2e - 16*log2e --
__global__ __launch_bounds__(256) void rearrange_bias(const float* __restrict__ in,
                                                      float* __restrict__ out) {
  int t = blockIdx.x * blockDim.x + threadIdx.x;  // 524288
  int r = t & 3, lane = (t >> 2) & 63, wm = (t >> 8) & 15;
  int jti = (t >> 12) & 15, qb = (t >> 16) & 7;
  int wave = wm >> 2, mt = wm & 3, quad = lane >> 4, l16 = lane & 15;
  int row = qb * 256 + wave * 64 + mt * 16 + quad * 4 + r;
  const float* src = in + (size_t)row * Sn + jti * 128 + l16;
  float4v o0, o1;
#pragma unroll
  for (int j = 0; j < 4; ++j) o0[j] = fmaf(src[j * 16], LOG2E, -C16);
#pragma unroll
  for (int j = 0; j < 4; ++j) o1[j] = fmaf(src[(j + 4) * 16], LOG2E, -C16);
  ((float4v*)out)[t * 2] = o0;
  ((float4v*)out)[t * 2 + 1] = o1;
}

// ------- fused QKV NT GEMM: grid (64, 24), Wqkv = [Wq;Wk;Wv] contiguous ------
// bn 0..7  -> Q  -> [B,H,S,64], d ^ (s&7)<<3           (A = xb)
// bn 8..15 -> K  -> [B,H,S,64], d ^ (s&7)<<3           (A = yb)
// bn 16..23-> V  -> [B,H,64,S], sigma+xor inner layout via LDS transpose (A=yb)
__global__ __launch_bounds__(256) void gemm_qkv(const __hip_bfloat16* __restrict__ Xb,
                                                const __hip_bfloat16* __restrict__ Yb,
                                                const __hip_bfloat16* __restrict__ Wqkv,
                                                __hip_bfloat16* __restrict__ Qb,
                                                __hip_bfloat16* __restrict__ Kb,
                                                __hip_bfloat16* __restrict__ Vtb) {
  constexpr int Kdim = 1024;
  __shared__ char pool[128 * 129 * 2];   // 33 KB: As+Bs during K-loop, stage after
  __hip_bfloat16* As = (__hip_bfloat16*)pool;
  __hip_bfloat16* Bs = As + 128 * 64;
  __hip_bfloat16* Sg = (__hip_bfloat16*)pool;  // stage[row*129 + col], aliased

  const int tid = threadIdx.x;
  const int wave = tid >> 6, lane = tid & 63;
  const int quad = lane >> 4, l16 = lane & 15;
  const int bm = blockIdx.x, bn = blockIdx.y;
  const int sel = bn >> 3;  // 0=Q 1=K 2=V
  const int wm = (wave & 1) * 64, wn = (wave >> 1) * 64;
  const __hip_bfloat16* A = (sel == 0) ? Xb : Yb;

  const __hip_bfloat16* aptr[4];
  const __hip_bfloat16* bptr[4];
#pragma unroll
  for (int i = 0; i < 4; ++i) {
    int c = wave * 4 + i;
    aptr[i] = A + (size_t)(bm * 128 + c * 8 + (lane >> 3)) * Kdim + (lane & 7) * 8;
    bptr[i] = Wqkv + (size_t)(bn * 128 + c * 8 + (lane >> 3)) * Kdim + (lane & 7) * 8;
  }

  float4v acc[4][4];
#pragma unroll
  for (int i = 0; i < 4; ++i)
#pragma unroll
    for (int j = 0; j < 4; ++j) acc[i][j] = (float4v){0.f, 0.f, 0.f, 0.f};

  for (int kt = 0; kt < Kdim / 64; ++kt) {
    __syncthreads();
#pragma unroll
    for (int i = 0; i < 4; ++i) {
      int c = wave * 4 + i;
      load_lds16(aptr[i] + kt * 64, &As[c * 512]);
      load_lds16(bptr[i] + kt * 64, &Bs[c * 512]);
    }
    __syncthreads();
#pragma unroll
    for (int ks = 0; ks < 2; ++ks) {
      short8 af[4], bf[4];
#pragma unroll
      for (int i = 0; i < 4; ++i)
        af[i] = *(const short8*)&As[(wm + i * 16 + l16) * 64 + ks * 32 + quad * 8];
#pragma unroll
      for (int j = 0; j < 4; ++j)
        bf[j] = *(const short8*)&Bs[(wn + j * 16 + l16) * 64 + ks * 32 + quad * 8];
#pragma unroll
      for (int i = 0; i < 4; ++i)
#pragma unroll
        for (int j = 0; j < 4; ++j)
          acc[i][j] = __builtin_amdgcn_mfma_f32_16x16x32_bf16(af[i], bf[j], acc[i][j], 0, 0, 0);
    }
  }

  const int b = bm >> 4;  // batch (16 s-tiles per batch)
  if (sel < 2) {
    // Q / K: granule-coalesced direct store
    __hip_bfloat16* dst = (sel == 0) ? Qb : Kb;
    const int nbase = (bn & 7) * 128;
#pragma unroll
    for (int i = 0; i < 4; ++i)
#pragma unroll
      for (int j = 0; j < 4; ++j)
#pragma unroll
        for (int r = 0; r < 4; ++r) {
          int row = bm * 128 + wm + i * 16 + quad * 4 + r;
          int col = nbase + wn + j * 16 + l16;
          int s = row & 2047, h = col >> 6, d = col & 63;
          int d2 = d ^ ((s & 7) << 3);
          dst[(((size_t)b * Hn + h) * Sn + s) * DEPTHn + d2] = __float2bfloat16(acc[i][j][r]);
        }
  } else {
    // V: LDS transpose -> coalesced b128 stores in sigma+xor layout
    __syncthreads();  // everyone done reading As/Bs
#pragma unroll
    for (int i = 0; i < 4; ++i)
#pragma unroll
      for (int j = 0; j < 4; ++j)
#pragma unroll
        for (int r = 0; r < 4; ++r) {
          int row = wm + i * 16 + quad * 4 + r;       // local s 0..127
          int col = wn + j * 16 + l16;                // local n 0..127
          Sg[row * 129 + col] = __float2bfloat16(acc[i][j][r]);
        }
    __syncthreads();
    const int s_tile = (bm & 15) * 128;
#pragma unroll
    for (int iter = 0; iter < 8; ++iter) {
      int id = iter * 256 + tid;        // 2048 b128 outputs
      int chunk = id & 15, lcol = id >> 4;
      int hg = (bn - 16) * 2 + (lcol >> 6), d = lcol & 63;
      int c = chunk ^ (d & 7);
      union { __hip_bfloat16 h[8]; short8 s8; } pu;
#pragma unroll
      for (int i = 0; i < 8; ++i) pu.h[i] = Sg[(i * 16 + c) * 129 + lcol];
      *(short8*)&Vtb[(((size_t)b * Hn + hg) * DEPTHn + d) * Sn + s_tile + chunk * 8] = pu.s8;
    }
  }
}

// ---------------- out-projection NT GEMM: fp32 output ----------------
__global__ __launch_bounds__(256) void gemm_out(const __hip_bfloat16* __restrict__ A,
                                                const __hip_bfloat16* __restrict__ B,
                                                float* __restrict__ Cf) {
  constexpr int Kdim = 1024;
  __shared__ __hip_bfloat16 As[128 * 64];
  __shared__ __hip_bfloat16 Bs[128 * 64];
  const int tid = threadIdx.x;
  const int wave = tid >> 6, lane = tid & 63;
  const int quad = lane >> 4, l16 = lane & 15;
  const int bm = blockIdx.x, bn = blockIdx.y;
  const int wm = (wave & 1) * 64, wn = (wave >> 1) * 64;

  const __hip_bfloat16* aptr[4];
  const __hip_bfloat16* bptr[4];
#pragma unroll
  for (int i = 0; i < 4; ++i) {
    int c = wave * 4 + i;
    aptr[i] = A + (size_t)(bm * 128 + c * 8 + (lane >> 3)) * Kdim + (lane & 7) * 8;
    bptr[i] = B + (size_t)(bn * 128 + c * 8 + (lane >> 3)) * Kdim + (lane & 7) * 8;
  }

  float4v acc[4][4];
#pragma unroll
  for (int i = 0; i < 4; ++i)
#pragma unroll
    for (int j = 0; j < 4; ++j) acc[i][j] = (float4v){0.f, 0.f, 0.f, 0.f};

  for (int kt = 0; kt < Kdim / 64; ++kt) {
    __syncthreads();
#pragma unroll
    for (int i = 0; i < 4; ++i) {
      int c = wave * 4 + i;
      load_lds16(aptr[i] + kt * 64, &As[c * 512]);
      load_lds16(bptr[i] + kt * 64, &Bs[c * 512]);
    }
    __syncthreads();
#pragma unroll
    for (int ks = 0; ks < 2; ++ks) {
      short8 af[4], bf[4];
#pragma unroll
      for (int i = 0; i < 4; ++i)
        af[i] = *(const short8*)&As[(wm + i * 16 + l16) * 64 + ks * 32 + quad * 8];
#pragma unroll
      for (int j = 0; j < 4; ++j)
        bf[j] = *(const short8*)&Bs[(wn + j * 16 + l16) * 64 + ks * 32 + quad * 8];
#pragma unroll
      for (int i = 0; i < 4; ++i)
#pragma unroll
        for (int j = 0; j < 4; ++j)
          acc[i][j] = __builtin_amdgcn_mfma_f32_16x16x32_bf16(af[i], bf[j], acc[i][j], 0, 0, 0);
    }
  }
#pragma unroll
  for (int i = 0; i < 4; ++i)
#pragma unroll
    for (int j = 0; j < 4; ++j)
#pragma unroll
      for (int r = 0; r < 4; ++r) {
        int row = bm * 128 + wm + i * 16 + quad * 4 + r;
        int col = bn * 128 + wn + j * 16 + l16;
        Cf[(size_t)row * 1024 + col] = acc[i][j][r];
      }
}

// ---------------- flash attention: 256 q-rows/block, sigma-packed P ----------
// 1-D grid 512, XCD-swizzled. PROVEN baseline: 162 us, 128 VGPR + ~128 AGPR
// (exactly the 256-total 2-wave/SIMD budget), 64 KB LDS -> 2 blocks/CU, no
// spill. DO NOT add state to this kernel incrementally: r2-r6 showed any
// addition either spills (WRITE_SIZE 550-600 MB) or drops to 1 block/CU.
// HIP __syncthreads drains vmcnt(0), so prefetch across the two per-tile
// barriers is structurally impossible here; a real pipeline needs a KVBLK=64
// full-double-buffer redesign (48 KB LDS, 1 barrier/tile) or P-in-registers.
__global__ __launch_bounds__(256, 2) void flash_attn(const __hip_bfloat16* __restrict__ Q,
                                                     const __hip_bfloat16* __restrict__ Kh,
                                                     const __hip_bfloat16* __restrict__ Vt,
                                                     const float* __restrict__ biasR,
                                                     __hip_bfloat16* __restrict__ O) {
  __shared__ __hip_bfloat16 Ks[128 * 64];     // 16 KB
  __shared__ __hip_bfloat16 Vts[64 * 128];    // 16 KB (sigma-ordered cols)
  __shared__ __hip_bfloat16 Ps[4][32 * 128];  // 32 KB, per-wave 32 rows
  const int tid = threadIdx.x;
  const int wave = tid >> 6, lane = tid & 63;
  const int quad = lane >> 4, l16 = lane & 15;
  const int swk = (l16 & 7) << 3;
  const int lin = blockIdx.x;
  const int bh = (lin & 7) * 8 + ((lin >> 3) & 7);   // XCD-locality swizzle
  const int qb = lin >> 6;
  const int q0 = qb * 256;
  const __hip_bfloat16* Qp = Q + (size_t)bh * Sn * DEPTHn;
  const __hip_bfloat16* Kp = Kh + (size_t)bh * Sn * DEPTHn;
  const __hip_bfloat16* Vp = Vt + (size_t)bh * DEPTHn * Sn;

  short8 qf[4][2];
#pragma unroll
  for (int mt = 0; mt < 4; ++mt)
#pragma unroll
    for (int ks = 0; ks < 2; ++ks)
      qf[mt][ks] = *(const short8*)&Qp[(size_t)(q0 + wave * 64 + mt * 16 + l16) * 64 +
                                       ((ks * 32 + quad * 8) ^ swk)];

  float l_i[4][4];
  float4v oacc[4][4];
#pragma unroll
  for (int mt = 0; mt < 4; ++mt)
#pragma unroll
    for (int r = 0; r < 4; ++r) l_i[mt][r] = 0.f;
#pragma unroll
  for (int mt = 0; mt < 4; ++mt)
#pragma unroll
    for (int nt = 0; nt < 4; ++nt) oacc[mt][nt] = (float4v){0.f, 0.f, 0.f, 0.f};

  const int koff = (lane >> 3) * 64 + (lane & 7) * 8;
  const int voff = (lane >> 4) * Sn + l16 * 8;

  for (int jti = 0; jti < 16; ++jti) {
    const int j0 = jti * 128;
    __syncthreads();
#pragma unroll
    for (int i = 0; i < 4; ++i) {
      int c = wave * 4 + i;
      load_lds16(Kp + (size_t)(j0 + c * 8) * 64 + koff, &Ks[c * 512]);
      load_lds16(Vp + (size_t)(c * 4) * Sn + j0 + voff, &Vts[c * 512]);
    }
    __syncthreads();

#pragma unroll
    for (int mtp = 0; mtp < 2; ++mtp) {
      float4v sacc[2][8];
#pragma unroll
      for (int m2 = 0; m2 < 2; ++m2)
#pragma unroll
        for (int jt = 0; jt < 8; ++jt) sacc[m2][jt] = (float4v){0.f, 0.f, 0.f, 0.f};
#pragma unroll
      for (int ks = 0; ks < 2; ++ks) {
        short8 kf[8];
#pragma unroll
        for (int jt = 0; jt < 8; ++jt)
          kf[jt] = *(const short8*)&Ks[(jt * 16 + l16) * 64 + ((ks * 32 + quad * 8) ^ swk)];
#pragma unroll
        for (int m2 = 0; m2 < 2; ++m2)
#pragma unroll
          for (int jt = 0; jt < 8; ++jt)
            sacc[m2][jt] = __builtin_amdgcn_mfma_f32_16x16x32_bf16(qf[mtp * 2 + m2][ks], kf[jt],
                                                                   sacc[m2][jt], 0, 0, 0);
      }

#pragma unroll
      for (int m2 = 0; m2 < 2; ++m2) {
        const int mt = mtp * 2 + m2;
        const float4v* bp = (const float4v*)biasR +
                            ((((size_t)(qb * 16 + jti) * 16 + wave * 4 + mt) * 64 + lane) << 3);
#pragma unroll
        for (int r = 0; r < 4; ++r) {
          float4v b0 = bp[r * 2], b1 = bp[r * 2 + 1];
          float ls = 0.f;
          union { __hip_bfloat16 h[8]; short8 s8; } pu;
#pragma unroll
          for (int jt = 0; jt < 8; ++jt) {
            float bb = (jt < 4) ? b0[jt] : b1[jt - 4];
            float p = __builtin_amdgcn_exp2f(fmaf(sacc[m2][jt][r], LOG2E, bb));
            ls += p;
            pu.h[jt] = __float2bfloat16(p);
          }
          l_i[mt][r] += ls;
          const int prow = m2 * 16 + quad * 4 + r;
          *(short8*)&Ps[wave][prow * 128 + ((l16 ^ (prow & 7)) << 3)] = pu.s8;
        }
      }

#pragma unroll
      for (int ks = 0; ks < 4; ++ks) {
        short8 vf[4];
#pragma unroll
        for (int nt = 0; nt < 4; ++nt)
          vf[nt] = *(const short8*)&Vts[(nt * 16 + l16) * 128 + ((ks * 32 + quad * 8) ^ swk)];
#pragma unroll
        for (int m2 = 0; m2 < 2; ++m2) {
          short8 pf = *(const short8*)&Ps[wave][(m2 * 16 + l16) * 128 +
                                               ((ks * 32 + quad * 8) ^ swk)];
#pragma unroll
          for (int nt = 0; nt < 4; ++nt)
            oacc[mtp * 2 + m2][nt] =
                __builtin_amdgcn_mfma_f32_16x16x32_bf16(pf, vf[nt], oacc[mtp * 2 + m2][nt], 0, 0, 0);
        }
      }
    }
  }

  const int b = bh >> 4, h = bh & 15;
#pragma unroll
  for (int mt = 0; mt < 4; ++mt) {
    float inv[4];
#pragma unroll
    for (int r = 0; r < 4; ++r) {
      float l = l_i[mt][r];
#pragma unroll
      for (int off = 1; off < 16; off <<= 1) l += __shfl_xor(l, off, 64);
      inv[r] = __builtin_amdgcn_rcpf(l);
    }
#pragma unroll
    for (int nt = 0; nt < 4; ++nt)
#pragma unroll
      for (int r = 0; r < 4; ++r) {
        int s = q0 + wave * 64 + mt * 16 + quad * 4 + r;
        int d = nt * 16 + l16;
        O[((size_t)b * Sn + s) * Dn + h * 64 + d] = __float2bfloat16(oacc[mt][nt][r] * inv[r]);
      }
  }
}

// ---------------- host ----------------
extern "C" void kernel_launch(void* const* d_in, const int* in_sizes, int n_in,
                              void* d_out, int out_size, void* d_ws, size_t ws_size,
                              hipStream_t stream) {
  const float* x = (const float*)d_in[0];
  const float* y = (const float*)d_in[1];
  const float* bias = (const float*)d_in[2];
  const float* Wq = (const float*)d_in[3];
  const float* Wk = (const float*)d_in[4];
  const float* Wv = (const float*)d_in[5];
  const float* Wo = (const float*)d_in[6];
  float* out = (float*)d_out;

  const size_t SZ_XY = (size_t)Bn * Sn * Dn * 2;     // 16 MB bf16
  const size_t SZ_W = (size_t)Dn * Dn * 2;           // 2 MB
  const size_t SZ_BIASF = (size_t)Sn * Sn * 4;       // 16 MB fp32

  char* p = (char*)d_ws;
  __hip_bfloat16* xb = (__hip_bfloat16*)p;      p += SZ_XY;   // xb,yb contiguous
  __hip_bfloat16* yb = (__hip_bfloat16*)p;      p += SZ_XY;
  __hip_bfloat16* wqkv = (__hip_bfloat16*)p;    p += 3 * SZ_W;  // Wq|Wk|Wv contiguous
  __hip_bfloat16* wob = (__hip_bfloat16*)p;     p += SZ_W;
  float* biasR = (float*)p;                     p += SZ_BIASF;
  __hip_bfloat16* Qb = (__hip_bfloat16*)p;      p += SZ_XY;
  __hip_bfloat16* Kb = (__hip_bfloat16*)p;      p += SZ_XY;
  __hip_bfloat16* Vtb = (__hip_bfloat16*)p;     p += SZ_XY;
  __hip_bfloat16* attnb = (__hip_bfloat16*)p;   p += SZ_XY;

  cast_xy<<<2 * 1048576 / 256, 256, 0, stream>>>(x, y, xb);
  cast_w<<<(4 * Dn * Dn / 8) / 256, 256, 0, stream>>>(Wq, Wk, Wv, Wo, wqkv);
  rearrange_bias<<<(Sn * Sn / 8) / 256, 256, 0, stream>>>(bias, biasR);

  gemm_qkv<<<dim3(64, 24), 256, 0, stream>>>(xb, yb, wqkv, Qb, Kb, Vtb);

  flash_attn<<<512, 256, 0, stream>>>(Qb, Kb, Vtb, biasR, attnb);

  gemm_out<<<dim3(64, 8), 256, 0, stream>>>(attnb, wob, out);
}